// Round 9
// baseline (650.619 us; speedup 1.0000x reference)
//
#include <hip/hip_runtime.h>

#define LEAKY 0.2f
#define LN_EPS 1e-5f
#define SM_EPS 1e-16f
#define CAP 64     // max in-degree bucket; deg ~ Poisson(16), P(>64) ~ 1e-18
#define WPAD 68    // LDS row stride (floats): multiple of 4 keeps float4 aligned

// ---- binned bucketing geometry ----
#define BIN_SHIFT 8          // 256 dsts per bin
#define MAXBINS   448        // supports N <= 114688; runtime fallback otherwise
#define CHUNK_A   7168       // edges per k_binA block (LDS ord = 56 KB)
#define BCAP      4608       // per-bin capacity; load ~Poisson(4096), +8 sigma
#define EMASK     0x1FFFFF   // e fits 21 bits (E <= 2M); dstLow in bits 21-28

// ---------------- K1: xl or xr = x @ W^T + b, W held in registers ----------------
// side = blockIdx.x & 1 selects {Wl->xl} or {Wr->xr}. 16 KB W staged through
// padded LDS once per block; lane i owns row i of W in 16 float4 VGPRs.
// Per node: 16 wave-uniform float4 x-loads (L1 broadcast) + 64 FMAs + one
// coalesced 256B store.
__global__ __launch_bounds__(256) void k_node_linear(
    const float* __restrict__ x,    // [N,64]
    const float* __restrict__ Wl,   // [64,64]
    const float* __restrict__ bl,   // [64]
    const float* __restrict__ Wr,   // [64,64]
    const float* __restrict__ br,   // [64]
    float* __restrict__ xl, float* __restrict__ xr, int N)
{
    __shared__ __align__(16) float sW[64 * WPAD];

    const int tid = threadIdx.x;
    const int side = blockIdx.x & 1;
    const float* __restrict__ W  = side ? Wr : Wl;
    const float* __restrict__ bv = side ? br : bl;
    float* __restrict__ dst      = side ? xr : xl;

    for (int i = tid; i < 4096; i += 256)
        sW[(i >> 6) * WPAD + (i & 63)] = W[i];
    __syncthreads();

    const int lane = tid & 63;
    float4 wq[16];
    #pragma unroll
    for (int q = 0; q < 16; ++q)
        wq[q] = *(const float4*)&sW[lane * WPAD + q * 4];
    const float bb = bv[lane];

    const int stream0 = (blockIdx.x >> 1) * 4 + (tid >> 6);
    const int nstream = (gridDim.x >> 1) * 4;
    for (int n = stream0; n < N; n += nstream) {
        const float4* xrow = (const float4*)(x + (long long)n * 64);
        float a = bb;
        #pragma unroll
        for (int q = 0; q < 16; ++q) {
            const float4 xv = xrow[q];
            const float4 w  = wq[q];
            a = fmaf(xv.x, w.x, fmaf(xv.y, w.y, fmaf(xv.z, w.z, fmaf(xv.w, w.w, a))));
        }
        dst[(long long)n * 64 + lane] = a;
    }
}

// ---------------- K2 legacy: direct scattered bucket (fallback only) ----------------
__global__ __launch_bounds__(256) void k_bucket(
    const int* __restrict__ ei, int* __restrict__ deg,
    int2* __restrict__ slot2, int E)
{
    const int e = blockIdx.x * 256 + threadIdx.x;
    if (e >= E) return;
    const int dst = ei[E + e];
    const int pos = atomicAdd(deg + dst, 1);
    if (pos < CAP) slot2[(long long)dst * CAP + pos] = make_int2(e, ei[e]);
}

// ---------------- K2a: coarse binning via LDS counting sort ----------------
// Streams BOTH ei rows (dst for binning, src carried along) so the gather
// kernel never touches ei again. Entry = {e | dstLow<<21, src}.
__global__ __launch_bounds__(256) void k_binA(
    const int* __restrict__ ei,      // [2,E]
    int* __restrict__ binCnt,        // [nbins] (pre-zeroed)
    int2* __restrict__ binArr,       // [nbins*BCAP] {packed, src}
    int E, int nbins)
{
    __shared__ int2 ord[CHUNK_A];
    __shared__ int cnt[MAXBINS], offs[MAXBINS], cur[MAXBINS], resB[MAXBINS];

    const int tid  = threadIdx.x;
    const int lane = tid & 63;
    const int ebase = blockIdx.x * CHUNK_A;
    const int nE = (E - ebase < CHUNK_A) ? (E - ebase) : CHUNK_A;
    const int* __restrict__ dstp = ei + E + ebase;
    const int* __restrict__ srcp = ei + ebase;

    for (int b = tid; b < MAXBINS; b += 256) { cnt[b] = 0; cur[b] = 0; }
    __syncthreads();

    // p1: count per bin
    for (int i = tid; i < nE; i += 256)
        atomicAdd(&cnt[dstp[i] >> BIN_SHIFT], 1);
    __syncthreads();

    // exclusive scan over MAXBINS (wave 0: 7 segments of 64, shfl_up scan)
    if (tid < 64) {
        int carry = 0;
        #pragma unroll
        for (int seg = 0; seg < MAXBINS / 64; ++seg) {
            const int v = cnt[seg * 64 + lane];
            int s = v;
            #pragma unroll
            for (int off = 1; off < 64; off <<= 1) {
                const int t = __shfl_up(s, off, 64);
                if (lane >= off) s += t;
            }
            offs[seg * 64 + lane] = carry + s - v;
            carry += __shfl(s, 63, 64);
        }
    }
    __syncthreads();

    // p2: place {packed, src} bin-ordered in LDS
    for (int i = tid; i < nE; i += 256) {
        const int d = dstp[i];
        const int b = d >> BIN_SHIFT;
        const int pos = atomicAdd(&cur[b], 1);
        ord[offs[b] + pos] =
            make_int2((ebase + i) | ((d & ((1 << BIN_SHIFT) - 1)) << 21), srcp[i]);
    }
    __syncthreads();

    // reserve global ranges (one atomic per non-empty bin per block)
    for (int b = tid; b < nbins; b += 256) {
        const int c = cnt[b];
        resB[b] = c ? atomicAdd(&binCnt[b], c) : 0;
    }
    __syncthreads();

    // coalesced copy-out: consecutive i are same-bin runs
    for (int i = tid; i < nE; i += 256) {
        const int2 p = ord[i];
        const int b = ((unsigned)p.x >> 21) + 0;  // dstLow only -> need bin from dst
        // recompute bin: dstLow is only low 8 bits; bin index must come from
        // position: i lies in [offs[b], offs[b]+cnt[b]) — recover via search-free
        // trick: store bin in cur[] pass? simpler: recompute from dstp not possible
        // (i is reordered). Instead carry bin implicitly: find b s.t. offs[b]<=i.
        // To avoid a search, we re-walk using the fact that copy-out order is
        // bin-ordered: use binary search over offs.
        int lo = 0, hi = nbins;            // offs is non-decreasing
        while (hi - lo > 1) {
            const int mid = (lo + hi) >> 1;
            if (offs[mid] <= i) lo = mid; else hi = mid;
        }
        const int k = resB[lo] + (i - offs[lo]);
        if (k < BCAP) binArr[(long long)lo * BCAP + k] = p;
    }
}

// ---------------- K2b: per-bin exact bucketing, coalesced deg/slot2 out ----------------
__global__ __launch_bounds__(256) void k_binB(
    const int* __restrict__ binCnt,
    const int2* __restrict__ binArr,
    int* __restrict__ deg,           // [N]
    int2* __restrict__ slot2,        // [N*CAP] {e, src}
    int N)
{
    __shared__ int2 ord2[BCAP];
    __shared__ int cnt2[256], offs2[256], cur2[256];

    const int b = blockIdx.x;
    const int tid  = threadIdx.x;
    const int lane = tid & 63;
    const int dst0 = b << BIN_SHIFT;
    int nb = binCnt[b];
    if (nb > BCAP) nb = BCAP;
    const int2* __restrict__ src = binArr + (long long)b * BCAP;

    cnt2[tid] = 0; cur2[tid] = 0;
    __syncthreads();

    for (int i = tid; i < nb; i += 256)
        atomicAdd(&cnt2[((unsigned)src[i].x >> 21) & 0xFF], 1);
    __syncthreads();

    if (tid < 64) {
        int carry = 0;
        #pragma unroll
        for (int seg = 0; seg < 4; ++seg) {
            const int v = cnt2[seg * 64 + lane];
            int s = v;
            #pragma unroll
            for (int off = 1; off < 64; off <<= 1) {
                const int t = __shfl_up(s, off, 64);
                if (lane >= off) s += t;
            }
            offs2[seg * 64 + lane] = carry + s - v;
            carry += __shfl(s, 63, 64);
        }
    }
    __syncthreads();

    for (int i = tid; i < nb; i += 256) {
        const int2 p = src[i];
        const int d = ((unsigned)p.x >> 21) & 0xFF;
        const int pos = atomicAdd(&cur2[d], 1);
        ord2[offs2[d] + pos] = make_int2(p.x & EMASK, p.y);  // {e, src}
    }
    __syncthreads();

    const int nd = (N - dst0 < 256) ? (N - dst0) : 256;
    if (tid < nd) deg[dst0 + tid] = cnt2[tid];

    // one wave per dst row: <=64 x 8B contiguous burst per row
    const int wv = tid >> 6;
    for (int d = wv; d < nd; d += 4) {
        int c = cnt2[d];
        if (c > CAP) c = CAP;
        if (lane < c) slot2[(long long)(dst0 + d) * CAP + lane] = ord2[offs2[d] + lane];
    }
}

// ---------------- K3: per-dst gather + softmax + aggregate + epilogue ----------------
// One 64-lane wave per destination node (4 nodes / 256-thread block).
// R9: slot2 carries {e, src} so the hoist is ONE coalesced int2 row read —
// the per-node slot->ei dependent gather (d scattered 128B lines + one
// latency level) is gone. Edge loop FROZEN at the R3 structure
// (persistent/DPP/1024-block variants all regressed: R4/R5/R7).
__global__ __launch_bounds__(256) void k_gather(
    const float* __restrict__ ea,    // [E,16]
    const float* __restrict__ We,    // [64,16]
    const float* __restrict__ att,   // [64]
    const float* __restrict__ xl, const float* __restrict__ xr,
    const int* __restrict__ deg, const int2* __restrict__ slot2,
    const float* __restrict__ x,
    const float* __restrict__ bias, const float* __restrict__ gamma,
    const float* __restrict__ beta,
    float* __restrict__ out, int N)
{
    const int lane = threadIdx.x & 63;
    const int n = blockIdx.x * 4 + (threadIdx.x >> 6);
    if (n >= N) return;

    const float4* w4 = (const float4*)(We + lane * 16);
    const float4 w0 = w4[0], w1 = w4[1], w2 = w4[2], w3 = w4[3];
    const float attv = att[lane];
    const float xrv = xr[(long long)n * 64 + lane];

    const int d = min(deg[n], CAP);

    // wave-wide index hoist: ONE coalesced 512B row read, no dependent gather
    int veid = 0, vsrc = 0;
    if (lane < d) {
        const int2 es = slot2[(long long)n * CAP + lane];
        veid = es.x;
        vsrc = es.y;
    }

    float acc = 0.f;
    float ns  = 0.f;

    float xlA = 0.f, xlB = 0.f;
    float4 a0, a1, a2, a3, b0, b1, b2, b3;
    a0 = a1 = a2 = a3 = b0 = b1 = b2 = b3 = make_float4(0.f, 0.f, 0.f, 0.f);

#define FETCH(j, XLV, E0, E1, E2, E3) do {                       \
        const int s_ = __shfl(vsrc, (j), 64);                    \
        const int e_ = __shfl(veid, (j), 64);                    \
        XLV = xl[(long long)s_ * 64 + lane];                     \
        const float4* p_ = (const float4*)(ea + (long long)e_ * 16); \
        E0 = p_[0]; E1 = p_[1]; E2 = p_[2]; E3 = p_[3];          \
    } while (0)

    if (d > 0) FETCH(0, xlA, a0, a1, a2, a3);
    if (d > 1) FETCH(1, xlB, b0, b1, b2, b3);

    for (int i = 0; i < d; ++i) {
        const float xlc = xlA;
        const float4 c0 = a0, c1 = a1, c2 = a2, c3 = a3;
        xlA = xlB; a0 = b0; a1 = b1; a2 = b2; a3 = b3;
        if (i + 2 < d) FETCH(i + 2, xlB, b0, b1, b2, b3);

        float ep = c0.x*w0.x + c0.y*w0.y + c0.z*w0.z + c0.w*w0.w
                 + c1.x*w1.x + c1.y*w1.y + c1.z*w1.z + c1.w*w1.w
                 + c2.x*w2.x + c2.y*w2.y + c2.z*w2.z + c2.w*w2.w
                 + c3.x*w3.x + c3.y*w3.y + c3.z*w3.z + c3.w*w3.w;
        float m = xlc + xrv + ep;
        m = (m > 0.f) ? m : LEAKY * m;           // leaky_relu
        float p = m * attv;
        p += __shfl_xor(p, 1, 64);
        p += __shfl_xor(p, 2, 64);
        p += __shfl_xor(p, 4, 64);
        const float ex = __expf(p);
        ns  += ex;
        acc = fmaf(ex, xlc, acc);
    }
#undef FETCH

    const float a = acc / (ns + SM_EPS);
    const float hv = a + bias[lane] + x[(long long)n * 64 + lane];

    float s = hv;
    #pragma unroll
    for (int off = 32; off; off >>= 1) s += __shfl_xor(s, off, 64);
    const float mu = s * (1.f / 64.f);
    const float dd = hv - mu;
    float v = dd * dd;
    #pragma unroll
    for (int off = 32; off; off >>= 1) v += __shfl_xor(v, off, 64);
    const float var = v * (1.f / 64.f);

    float hn = dd * rsqrtf(var + LN_EPS) * gamma[lane] + beta[lane];
    out[(long long)n * 64 + lane] = (hn > 0.f) ? hn : 0.f;
}

extern "C" void kernel_launch(void* const* d_in, const int* in_sizes, int n_in,
                              void* d_out, int out_size, void* d_ws, size_t ws_size,
                              hipStream_t stream) {
    (void)n_in; (void)out_size;

    const float* x     = (const float*)d_in[0];
    const int*   ei    = (const int*)d_in[1];
    const float* ea    = (const float*)d_in[2];
    const float* Wl    = (const float*)d_in[3];
    const float* bl    = (const float*)d_in[4];
    const float* Wr    = (const float*)d_in[5];
    const float* br    = (const float*)d_in[6];
    const float* We    = (const float*)d_in[7];
    const float* att   = (const float*)d_in[8];
    const float* bias  = (const float*)d_in[9];
    const float* gamma = (const float*)d_in[10];
    const float* beta  = (const float*)d_in[11];

    const int N = in_sizes[0] / 64;   // x is [N,64]
    const int E = in_sizes[1] / 2;    // edge_index is [2,E]
    const int nbins = (N + (1 << BIN_SHIFT) - 1) >> BIN_SHIFT;

    // ws layout: xl, xr, deg[N], binCnt[MAXBINS], slot2[N*CAP] int2, binArr int2
    float* w = (float*)d_ws;
    float* xl   = w;                      w += (size_t)N * 64;
    float* xr   = w;                      w += (size_t)N * 64;
    int* deg    = (int*)w;
    int* binCnt = deg + N;
    int2* slot2 = (int2*)(binCnt + MAXBINS);
    int2* binArr = slot2 + (size_t)N * CAP;
    const size_t needed = ((char*)(binArr + (size_t)nbins * BCAP)) - (char*)d_ws;

    float* out = (float*)d_out;

    const bool binned = (nbins <= MAXBINS) && (E <= (1 << 21)) &&
                        (ws_size >= needed);

    hipMemsetAsync(deg, 0, ((size_t)N + MAXBINS) * sizeof(int), stream);

    k_node_linear<<<2048, 256, 0, stream>>>(x, Wl, bl, Wr, br, xl, xr, N);

    if (binned) {
        const int nbA = (E + CHUNK_A - 1) / CHUNK_A;
        k_binA<<<nbA, 256, 0, stream>>>(ei, binCnt, binArr, E, nbins);
        k_binB<<<nbins, 256, 0, stream>>>(binCnt, binArr, deg, slot2, N);
    } else {
        k_bucket<<<(E + 255) / 256, 256, 0, stream>>>(ei, deg, slot2, E);
    }

    k_gather<<<(N + 3) / 4, 256, 0, stream>>>(
        ea, We, att, xl, xr, deg, slot2, x, bias, gamma, beta, out, N);
}

// Round 11
// 645.921 us; speedup vs baseline: 1.0073x; 1.0073x over previous
//
#include <hip/hip_runtime.h>

#define LEAKY 0.2f
#define LN_EPS 1e-5f
#define SM_EPS 1e-16f
#define CAP 64     // max in-degree bucket; deg ~ Poisson(16), P(>64) ~ 1e-18
#define WPAD 68    // LDS row stride (floats): multiple of 4 keeps float4 aligned

// ---- binned bucketing geometry ----
#define BIN_SHIFT 8          // 256 dsts per bin
#define MAXBINS   448        // supports N <= 114688; runtime fallback otherwise
#define CHUNK_A   7168       // edges per k_binA block (LDS ord = 56 KB)
#define BCAP      4608       // per-bin capacity; load ~Poisson(4096), +8 sigma
#define EMASK     0x1FFFFF   // e fits 21 bits (E <= 2M); dstLow in bits 21-28

// ---------------- K1: xl or xr = x @ W^T + b, W held in registers ----------------
// side = blockIdx.x & 1 selects {Wl->xl} or {Wr->xr}. 16 KB W staged through
// padded LDS once per block; lane i owns row i of W in 16 float4 VGPRs.
// Per node: 16 wave-uniform float4 x-loads (L1 broadcast) + 64 FMAs + one
// coalesced 256B store.
__global__ __launch_bounds__(256) void k_node_linear(
    const float* __restrict__ x,    // [N,64]
    const float* __restrict__ Wl,   // [64,64]
    const float* __restrict__ bl,   // [64]
    const float* __restrict__ Wr,   // [64,64]
    const float* __restrict__ br,   // [64]
    float* __restrict__ xl, float* __restrict__ xr, int N)
{
    __shared__ __align__(16) float sW[64 * WPAD];

    const int tid = threadIdx.x;
    const int side = blockIdx.x & 1;
    const float* __restrict__ W  = side ? Wr : Wl;
    const float* __restrict__ bv = side ? br : bl;
    float* __restrict__ dst      = side ? xr : xl;

    for (int i = tid; i < 4096; i += 256)
        sW[(i >> 6) * WPAD + (i & 63)] = W[i];
    __syncthreads();

    const int lane = tid & 63;
    float4 wq[16];
    #pragma unroll
    for (int q = 0; q < 16; ++q)
        wq[q] = *(const float4*)&sW[lane * WPAD + q * 4];
    const float bb = bv[lane];

    const int stream0 = (blockIdx.x >> 1) * 4 + (tid >> 6);
    const int nstream = (gridDim.x >> 1) * 4;
    for (int n = stream0; n < N; n += nstream) {
        const float4* xrow = (const float4*)(x + (long long)n * 64);
        float a = bb;
        #pragma unroll
        for (int q = 0; q < 16; ++q) {
            const float4 xv = xrow[q];
            const float4 w  = wq[q];
            a = fmaf(xv.x, w.x, fmaf(xv.y, w.y, fmaf(xv.z, w.z, fmaf(xv.w, w.w, a))));
        }
        dst[(long long)n * 64 + lane] = a;
    }
}

// ---------------- K2 legacy: direct scattered bucket (fallback only) ----------------
__global__ __launch_bounds__(256) void k_bucket(
    const int* __restrict__ ei, int* __restrict__ deg,
    int2* __restrict__ slot2, int E)
{
    const int e = blockIdx.x * 256 + threadIdx.x;
    if (e >= E) return;
    const int dst = ei[E + e];
    const int pos = atomicAdd(deg + dst, 1);
    if (pos < CAP) slot2[(long long)dst * CAP + pos] = make_int2(e, ei[e]);
}

// ---------------- K2a: coarse binning via LDS counting sort ----------------
// Streams BOTH ei rows (dst for binning, src carried along) so the gather
// kernel never touches ei again. Entry = {e | dstLow<<21, src}.
// R10: copy-out iterates BIN RUNS (wave round-robin over bins, coalesced
// bursts) — R9's per-edge binary search (9 LDS reads/edge) removed.
__global__ __launch_bounds__(256) void k_binA(
    const int* __restrict__ ei,      // [2,E]
    int* __restrict__ binCnt,        // [nbins] (pre-zeroed)
    int2* __restrict__ binArr,       // [nbins*BCAP] {packed, src}
    int E, int nbins)
{
    __shared__ int2 ord[CHUNK_A];
    __shared__ int cnt[MAXBINS], offs[MAXBINS], cur[MAXBINS], resB[MAXBINS];

    const int tid  = threadIdx.x;
    const int lane = tid & 63;
    const int ebase = blockIdx.x * CHUNK_A;
    const int nE = (E - ebase < CHUNK_A) ? (E - ebase) : CHUNK_A;
    const int* __restrict__ dstp = ei + E + ebase;
    const int* __restrict__ srcp = ei + ebase;

    for (int b = tid; b < MAXBINS; b += 256) { cnt[b] = 0; cur[b] = 0; }
    __syncthreads();

    // p1: count per bin
    for (int i = tid; i < nE; i += 256)
        atomicAdd(&cnt[dstp[i] >> BIN_SHIFT], 1);
    __syncthreads();

    // exclusive scan over MAXBINS (wave 0: 7 segments of 64, shfl_up scan)
    if (tid < 64) {
        int carry = 0;
        #pragma unroll
        for (int seg = 0; seg < MAXBINS / 64; ++seg) {
            const int v = cnt[seg * 64 + lane];
            int s = v;
            #pragma unroll
            for (int off = 1; off < 64; off <<= 1) {
                const int t = __shfl_up(s, off, 64);
                if (lane >= off) s += t;
            }
            offs[seg * 64 + lane] = carry + s - v;
            carry += __shfl(s, 63, 64);
        }
    }
    __syncthreads();

    // p2: place {packed, src} bin-ordered in LDS
    for (int i = tid; i < nE; i += 256) {
        const int d = dstp[i];
        const int b = d >> BIN_SHIFT;
        const int pos = atomicAdd(&cur[b], 1);
        ord[offs[b] + pos] =
            make_int2((ebase + i) | ((d & ((1 << BIN_SHIFT) - 1)) << 21), srcp[i]);
    }
    __syncthreads();

    // reserve global ranges (one atomic per non-empty bin per block)
    for (int b = tid; b < nbins; b += 256) {
        const int c = cnt[b];
        resB[b] = c ? atomicAdd(&binCnt[b], c) : 0;
    }
    __syncthreads();

    // copy-out by bin run: wave wv handles bins wv, wv+4, ... (avg run ~18)
    const int wv = tid >> 6;
    for (int b = wv; b < nbins; b += 4) {
        const int c = cnt[b], o = offs[b], r = resB[b];
        for (int k = lane; k < c; k += 64) {
            const int kk = r + k;
            if (kk < BCAP) binArr[(long long)b * BCAP + kk] = ord[o + k];
        }
    }
}

// ---------------- K2b: per-bin exact bucketing, coalesced deg/slot2 out ----------------
__global__ __launch_bounds__(256) void k_binB(
    const int* __restrict__ binCnt,
    const int2* __restrict__ binArr,
    int* __restrict__ deg,           // [N]
    int2* __restrict__ slot2,        // [N*CAP] {e, src}
    int N)
{
    __shared__ int2 ord2[BCAP];
    __shared__ int cnt2[256], offs2[256], cur2[256];

    const int b = blockIdx.x;
    const int tid  = threadIdx.x;
    const int lane = tid & 63;
    const int dst0 = b << BIN_SHIFT;
    int nb = binCnt[b];
    if (nb > BCAP) nb = BCAP;
    const int2* __restrict__ src = binArr + (long long)b * BCAP;

    cnt2[tid] = 0; cur2[tid] = 0;
    __syncthreads();

    for (int i = tid; i < nb; i += 256)
        atomicAdd(&cnt2[((unsigned)src[i].x >> 21) & 0xFF], 1);
    __syncthreads();

    if (tid < 64) {
        int carry = 0;
        #pragma unroll
        for (int seg = 0; seg < 4; ++seg) {
            const int v = cnt2[seg * 64 + lane];
            int s = v;
            #pragma unroll
            for (int off = 1; off < 64; off <<= 1) {
                const int t = __shfl_up(s, off, 64);
                if (lane >= off) s += t;
            }
            offs2[seg * 64 + lane] = carry + s - v;
            carry += __shfl(s, 63, 64);
        }
    }
    __syncthreads();

    for (int i = tid; i < nb; i += 256) {
        const int2 p = src[i];
        const int d = ((unsigned)p.x >> 21) & 0xFF;
        const int pos = atomicAdd(&cur2[d], 1);
        ord2[offs2[d] + pos] = make_int2(p.x & EMASK, p.y);  // {e, src}
    }
    __syncthreads();

    const int nd = (N - dst0 < 256) ? (N - dst0) : 256;
    if (tid < nd) deg[dst0 + tid] = cnt2[tid];

    // one wave per dst row: <=64 x 8B contiguous burst per row
    const int wv = tid >> 6;
    for (int d = wv; d < nd; d += 4) {
        int c = cnt2[d];
        if (c > CAP) c = CAP;
        if (lane < c) slot2[(long long)(dst0 + d) * CAP + lane] = ord2[offs2[d] + lane];
    }
}

// ---------------- K3: per-dst gather + softmax + aggregate + epilogue ----------------
// One 64-lane wave per destination node (4 nodes / 256-thread block).
// slot2 carries {e, src}: the hoist is ONE coalesced int2 row read.
// R10: edge loop unrolled by 2 with A/B role swap — same depth-2 pipeline,
// same __shfl broadcasts, same edge order (bitwise identical), but the
// 17-register stage shift (17 v_mov/edge ~ 34cy of the ~92cy issue budget)
// is gone. (R5's rotation failed because it ALSO swapped shfl->readlane and
// the reduce->DPP; this changes loop structure only.)
__global__ __launch_bounds__(256) void k_gather(
    const float* __restrict__ ea,    // [E,16]
    const float* __restrict__ We,    // [64,16]
    const float* __restrict__ att,   // [64]
    const float* __restrict__ xl, const float* __restrict__ xr,
    const int* __restrict__ deg, const int2* __restrict__ slot2,
    const float* __restrict__ x,
    const float* __restrict__ bias, const float* __restrict__ gamma,
    const float* __restrict__ beta,
    float* __restrict__ out, int N)
{
    const int lane = threadIdx.x & 63;
    const int n = blockIdx.x * 4 + (threadIdx.x >> 6);
    if (n >= N) return;

    const float4* w4 = (const float4*)(We + lane * 16);
    const float4 w0 = w4[0], w1 = w4[1], w2 = w4[2], w3 = w4[3];
    const float attv = att[lane];
    const float xrv = xr[(long long)n * 64 + lane];

    const int d = min(deg[n], CAP);

    // wave-wide index hoist: ONE coalesced 512B row read, no dependent gather
    int veid = 0, vsrc = 0;
    if (lane < d) {
        const int2 es = slot2[(long long)n * CAP + lane];
        veid = es.x;
        vsrc = es.y;
    }

    float acc = 0.f;
    float ns  = 0.f;

    float xlA = 0.f, xlB = 0.f;
    float4 a0, a1, a2, a3, b0, b1, b2, b3;
    a0 = a1 = a2 = a3 = b0 = b1 = b2 = b3 = make_float4(0.f, 0.f, 0.f, 0.f);

#define FETCH(j, XLV, E0, E1, E2, E3) do {                       \
        const int s_ = __shfl(vsrc, (j), 64);                    \
        const int e_ = __shfl(veid, (j), 64);                    \
        XLV = xl[(long long)s_ * 64 + lane];                     \
        const float4* p_ = (const float4*)(ea + (long long)e_ * 16); \
        E0 = p_[0]; E1 = p_[1]; E2 = p_[2]; E3 = p_[3];          \
    } while (0)

#define COMPUTE(XLV, E0, E1, E2, E3) do {                        \
        float ep = E0.x*w0.x + E0.y*w0.y + E0.z*w0.z + E0.w*w0.w \
                 + E1.x*w1.x + E1.y*w1.y + E1.z*w1.z + E1.w*w1.w \
                 + E2.x*w2.x + E2.y*w2.y + E2.z*w2.z + E2.w*w2.w \
                 + E3.x*w3.x + E3.y*w3.y + E3.z*w3.z + E3.w*w3.w;\
        float m = XLV + xrv + ep;                                \
        m = (m > 0.f) ? m : LEAKY * m;   /* leaky_relu */        \
        float p = m * attv;                                      \
        p += __shfl_xor(p, 1, 64);                               \
        p += __shfl_xor(p, 2, 64);                               \
        p += __shfl_xor(p, 4, 64);                               \
        const float ex = __expf(p);                              \
        ns  += ex;                                               \
        acc = fmaf(ex, XLV, acc);                                \
    } while (0)

    if (d > 0) FETCH(0, xlA, a0, a1, a2, a3);
    if (d > 1) FETCH(1, xlB, b0, b1, b2, b3);

    for (int i = 0; i < d; i += 2) {
        COMPUTE(xlA, a0, a1, a2, a3);
        if (i + 2 < d) FETCH(i + 2, xlA, a0, a1, a2, a3);
        if (i + 1 < d) {
            COMPUTE(xlB, b0, b1, b2, b3);
            if (i + 3 < d) FETCH(i + 3, xlB, b0, b1, b2, b3);
        }
    }
#undef FETCH
#undef COMPUTE

    const float a = acc / (ns + SM_EPS);
    const float hv = a + bias[lane] + x[(long long)n * 64 + lane];

    float s = hv;
    #pragma unroll
    for (int off = 32; off; off >>= 1) s += __shfl_xor(s, off, 64);
    const float mu = s * (1.f / 64.f);
    const float dd = hv - mu;
    float v = dd * dd;
    #pragma unroll
    for (int off = 32; off; off >>= 1) v += __shfl_xor(v, off, 64);
    const float var = v * (1.f / 64.f);

    float hn = dd * rsqrtf(var + LN_EPS) * gamma[lane] + beta[lane];
    out[(long long)n * 64 + lane] = (hn > 0.f) ? hn : 0.f;
}

extern "C" void kernel_launch(void* const* d_in, const int* in_sizes, int n_in,
                              void* d_out, int out_size, void* d_ws, size_t ws_size,
                              hipStream_t stream) {
    (void)n_in; (void)out_size;

    const float* x     = (const float*)d_in[0];
    const int*   ei    = (const int*)d_in[1];
    const float* ea    = (const float*)d_in[2];
    const float* Wl    = (const float*)d_in[3];
    const float* bl    = (const float*)d_in[4];
    const float* Wr    = (const float*)d_in[5];
    const float* br    = (const float*)d_in[6];
    const float* We    = (const float*)d_in[7];
    const float* att   = (const float*)d_in[8];
    const float* bias  = (const float*)d_in[9];
    const float* gamma = (const float*)d_in[10];
    const float* beta  = (const float*)d_in[11];

    const int N = in_sizes[0] / 64;   // x is [N,64]
    const int E = in_sizes[1] / 2;    // edge_index is [2,E]
    const int nbins = (N + (1 << BIN_SHIFT) - 1) >> BIN_SHIFT;

    // ws layout: xl, xr, deg[N], binCnt[MAXBINS], slot2[N*CAP] int2, binArr int2
    float* w = (float*)d_ws;
    float* xl   = w;                      w += (size_t)N * 64;
    float* xr   = w;                      w += (size_t)N * 64;
    int* deg    = (int*)w;
    int* binCnt = deg + N;
    int2* slot2 = (int2*)(binCnt + MAXBINS);
    int2* binArr = slot2 + (size_t)N * CAP;
    const size_t needed = ((char*)(binArr + (size_t)nbins * BCAP)) - (char*)d_ws;

    float* out = (float*)d_out;

    const bool binned = (nbins <= MAXBINS) && (E <= (1 << 21)) &&
                        (ws_size >= needed);

    hipMemsetAsync(deg, 0, ((size_t)N + MAXBINS) * sizeof(int), stream);

    k_node_linear<<<2048, 256, 0, stream>>>(x, Wl, bl, Wr, br, xl, xr, N);

    if (binned) {
        const int nbA = (E + CHUNK_A - 1) / CHUNK_A;
        k_binA<<<nbA, 256, 0, stream>>>(ei, binCnt, binArr, E, nbins);
        k_binB<<<nbins, 256, 0, stream>>>(binCnt, binArr, deg, slot2, N);
    } else {
        k_bucket<<<(E + 255) / 256, 256, 0, stream>>>(ei, deg, slot2, E);
    }

    k_gather<<<(N + 3) / 4, 256, 0, stream>>>(
        ea, We, att, xl, xr, deg, slot2, x, bias, gamma, beta, out, N);
}

// Round 12
// 620.823 us; speedup vs baseline: 1.0480x; 1.0404x over previous
//
#include <hip/hip_runtime.h>

#define LEAKY 0.2f
#define LN_EPS 1e-5f
#define SM_EPS 1e-16f
#define CAP 64     // max in-degree bucket; deg ~ Poisson(16), P(>64) ~ 1e-18
#define WPAD 68    // LDS row stride (floats): multiple of 4 keeps float4 aligned

// ---- binned bucketing geometry ----
#define BIN_SHIFT 8          // 256 dsts per bin
#define MAXBINS   448        // supports N <= 114688; runtime fallback otherwise
#define CHUNK_A   5632       // edges per k_binA block (ord 44KB + ordBin 11KB + tbl 7KB < 64KB)
#define BCAP      4608       // per-bin capacity; load ~Poisson(4096), +8 sigma
#define EMASK     0x1FFFFF   // e fits 21 bits (E <= 2M); dstLow in bits 21-28
#define NPW       4          // nodes per wave in k_gather

// ---------------- K1: xl or xr = x @ W^T + b, W held in registers ----------------
__global__ __launch_bounds__(256) void k_node_linear(
    const float* __restrict__ x,    // [N,64]
    const float* __restrict__ Wl,   // [64,64]
    const float* __restrict__ bl,   // [64]
    const float* __restrict__ Wr,   // [64,64]
    const float* __restrict__ br,   // [64]
    float* __restrict__ xl, float* __restrict__ xr, int N)
{
    __shared__ __align__(16) float sW[64 * WPAD];

    const int tid = threadIdx.x;
    const int side = blockIdx.x & 1;
    const float* __restrict__ W  = side ? Wr : Wl;
    const float* __restrict__ bv = side ? br : bl;
    float* __restrict__ dst      = side ? xr : xl;

    for (int i = tid; i < 4096; i += 256)
        sW[(i >> 6) * WPAD + (i & 63)] = W[i];
    __syncthreads();

    const int lane = tid & 63;
    float4 wq[16];
    #pragma unroll
    for (int q = 0; q < 16; ++q)
        wq[q] = *(const float4*)&sW[lane * WPAD + q * 4];
    const float bb = bv[lane];

    const int stream0 = (blockIdx.x >> 1) * 4 + (tid >> 6);
    const int nstream = (gridDim.x >> 1) * 4;
    for (int n = stream0; n < N; n += nstream) {
        const float4* xrow = (const float4*)(x + (long long)n * 64);
        float a = bb;
        #pragma unroll
        for (int q = 0; q < 16; ++q) {
            const float4 xv = xrow[q];
            const float4 w  = wq[q];
            a = fmaf(xv.x, w.x, fmaf(xv.y, w.y, fmaf(xv.z, w.z, fmaf(xv.w, w.w, a))));
        }
        dst[(long long)n * 64 + lane] = a;
    }
}

// ---------------- K2 legacy: direct scattered bucket (fallback only) ----------------
__global__ __launch_bounds__(256) void k_bucket(
    const int* __restrict__ ei, int* __restrict__ deg,
    int2* __restrict__ slot2, int E)
{
    const int e = blockIdx.x * 256 + threadIdx.x;
    if (e >= E) return;
    const int dst = ei[E + e];
    const int pos = atomicAdd(deg + dst, 1);
    if (pos < CAP) slot2[(long long)dst * CAP + pos] = make_int2(e, ei[e]);
}

// ---------------- K2a: coarse binning via LDS counting sort ----------------
// Streams BOTH ei rows (dst for binning, src carried along). Entry =
// {e | dstLow<<21, src}. R12: copy-out back to the per-edge COALESCED form
// (R8-style) — bin recorded per entry in ordBin[] u16 at placement time, so
// no search (R9) and no 18/64-lane run bursts (R10/R11).
__global__ __launch_bounds__(256) void k_binA(
    const int* __restrict__ ei,      // [2,E]
    int* __restrict__ binCnt,        // [nbins] (pre-zeroed)
    int2* __restrict__ binArr,       // [nbins*BCAP] {packed, src}
    int E, int nbins)
{
    __shared__ int2 ord[CHUNK_A];
    __shared__ unsigned short ordBin[CHUNK_A];
    __shared__ int cnt[MAXBINS], offs[MAXBINS], cur[MAXBINS], resB[MAXBINS];

    const int tid  = threadIdx.x;
    const int lane = tid & 63;
    const int ebase = blockIdx.x * CHUNK_A;
    const int nE = (E - ebase < CHUNK_A) ? (E - ebase) : CHUNK_A;
    const int* __restrict__ dstp = ei + E + ebase;
    const int* __restrict__ srcp = ei + ebase;

    for (int b = tid; b < MAXBINS; b += 256) { cnt[b] = 0; cur[b] = 0; }
    __syncthreads();

    // p1: count per bin
    for (int i = tid; i < nE; i += 256)
        atomicAdd(&cnt[dstp[i] >> BIN_SHIFT], 1);
    __syncthreads();

    // exclusive scan over MAXBINS (wave 0: 7 segments of 64, shfl_up scan)
    if (tid < 64) {
        int carry = 0;
        #pragma unroll
        for (int seg = 0; seg < MAXBINS / 64; ++seg) {
            const int v = cnt[seg * 64 + lane];
            int s = v;
            #pragma unroll
            for (int off = 1; off < 64; off <<= 1) {
                const int t = __shfl_up(s, off, 64);
                if (lane >= off) s += t;
            }
            offs[seg * 64 + lane] = carry + s - v;
            carry += __shfl(s, 63, 64);
        }
    }
    __syncthreads();

    // p2: place {packed, src} bin-ordered in LDS; record bin per slot
    for (int i = tid; i < nE; i += 256) {
        const int d = dstp[i];
        const int b = d >> BIN_SHIFT;
        const int pos = atomicAdd(&cur[b], 1);
        const int at = offs[b] + pos;
        ord[at] = make_int2((ebase + i) | ((d & ((1 << BIN_SHIFT) - 1)) << 21), srcp[i]);
        ordBin[at] = (unsigned short)b;
    }
    __syncthreads();

    // reserve global ranges (one atomic per non-empty bin per block)
    for (int b = tid; b < nbins; b += 256) {
        const int c = cnt[b];
        resB[b] = c ? atomicAdd(&binCnt[b], c) : 0;
    }
    __syncthreads();

    // per-edge coalesced copy-out: consecutive i -> same-bin runs
    for (int i = tid; i < nE; i += 256) {
        const int b = ordBin[i];
        const int k = resB[b] + (i - offs[b]);
        if (k < BCAP) binArr[(long long)b * BCAP + k] = ord[i];
    }
}

// ---------------- K2b: per-bin exact bucketing, coalesced deg/slot2 out ----------------
__global__ __launch_bounds__(256) void k_binB(
    const int* __restrict__ binCnt,
    const int2* __restrict__ binArr,
    int* __restrict__ deg,           // [N]
    int2* __restrict__ slot2,        // [N*CAP] {e, src}
    int N)
{
    __shared__ int2 ord2[BCAP];
    __shared__ int cnt2[256], offs2[256], cur2[256];

    const int b = blockIdx.x;
    const int tid  = threadIdx.x;
    const int lane = tid & 63;
    const int dst0 = b << BIN_SHIFT;
    int nb = binCnt[b];
    if (nb > BCAP) nb = BCAP;
    const int2* __restrict__ src = binArr + (long long)b * BCAP;

    cnt2[tid] = 0; cur2[tid] = 0;
    __syncthreads();

    for (int i = tid; i < nb; i += 256)
        atomicAdd(&cnt2[((unsigned)src[i].x >> 21) & 0xFF], 1);
    __syncthreads();

    if (tid < 64) {
        int carry = 0;
        #pragma unroll
        for (int seg = 0; seg < 4; ++seg) {
            const int v = cnt2[seg * 64 + lane];
            int s = v;
            #pragma unroll
            for (int off = 1; off < 64; off <<= 1) {
                const int t = __shfl_up(s, off, 64);
                if (lane >= off) s += t;
            }
            offs2[seg * 64 + lane] = carry + s - v;
            carry += __shfl(s, 63, 64);
        }
    }
    __syncthreads();

    for (int i = tid; i < nb; i += 256) {
        const int2 p = src[i];
        const int d = ((unsigned)p.x >> 21) & 0xFF;
        const int pos = atomicAdd(&cur2[d], 1);
        ord2[offs2[d] + pos] = make_int2(p.x & EMASK, p.y);  // {e, src}
    }
    __syncthreads();

    const int nd = (N - dst0 < 256) ? (N - dst0) : 256;
    if (tid < nd) deg[dst0 + tid] = cnt2[tid];

    // one wave per dst row: <=64 x 8B contiguous burst per row
    const int wv = tid >> 6;
    for (int d = wv; d < nd; d += 4) {
        int c = cnt2[d];
        if (c > CAP) c = CAP;
        if (lane < c) slot2[(long long)(dst0 + d) * CAP + lane] = ord2[offs2[d] + lane];
    }
}

// ---------------- K3: per-dst gather + softmax + aggregate + epilogue ----------------
// R12: each WAVE processes NPW=4 consecutive nodes; blocks stay 256-thread
// (4 waves, dynamic dispatch). Rationale (Little's law on R3-R11 counters):
// resident ~1024 blocks x 13us each = 318us; more waves/block (R7) loses to
// the max-of-16-Poisson tail (+55%); more nodes/wave sums the work first
// (Poisson(64), max-of-4 tail +16%) and cuts block count 4x. Per-node inner
// loop byte-frozen at the R11 form (unroll-2, proven arithmetic-identical).
__global__ __launch_bounds__(256) void k_gather(
    const float* __restrict__ ea,    // [E,16]
    const float* __restrict__ We,    // [64,16]
    const float* __restrict__ att,   // [64]
    const float* __restrict__ xl, const float* __restrict__ xr,
    const int* __restrict__ deg, const int2* __restrict__ slot2,
    const float* __restrict__ x,
    const float* __restrict__ bias, const float* __restrict__ gamma,
    const float* __restrict__ beta,
    float* __restrict__ out, int N)
{
    const int lane = threadIdx.x & 63;
    const int wid  = blockIdx.x * 4 + (threadIdx.x >> 6);
    const int n0   = wid * NPW;
    if (n0 >= N) return;

    // wave-lifetime constants
    const float4* w4 = (const float4*)(We + lane * 16);
    const float4 w0 = w4[0], w1 = w4[1], w2 = w4[2], w3 = w4[3];
    const float attv  = att[lane];
    const float biasv = bias[lane];
    const float gv    = gamma[lane];
    const float bev   = beta[lane];

    for (int j = 0; j < NPW; ++j) {
        const int n = n0 + j;
        if (n >= N) break;

        const float xrv = xr[(long long)n * 64 + lane];
        const int d = min(deg[n], CAP);

        // wave-wide index hoist: ONE coalesced 512B row read
        int veid = 0, vsrc = 0;
        if (lane < d) {
            const int2 es = slot2[(long long)n * CAP + lane];
            veid = es.x;
            vsrc = es.y;
        }

        float acc = 0.f;
        float ns  = 0.f;

        float xlA = 0.f, xlB = 0.f;
        float4 a0, a1, a2, a3, b0, b1, b2, b3;
        a0 = a1 = a2 = a3 = b0 = b1 = b2 = b3 = make_float4(0.f, 0.f, 0.f, 0.f);

#define FETCH(jj, XLV, E0, E1, E2, E3) do {                      \
        const int s_ = __shfl(vsrc, (jj), 64);                   \
        const int e_ = __shfl(veid, (jj), 64);                   \
        XLV = xl[(long long)s_ * 64 + lane];                     \
        const float4* p_ = (const float4*)(ea + (long long)e_ * 16); \
        E0 = p_[0]; E1 = p_[1]; E2 = p_[2]; E3 = p_[3];          \
    } while (0)

#define COMPUTE(XLV, E0, E1, E2, E3) do {                        \
        float ep = E0.x*w0.x + E0.y*w0.y + E0.z*w0.z + E0.w*w0.w \
                 + E1.x*w1.x + E1.y*w1.y + E1.z*w1.z + E1.w*w1.w \
                 + E2.x*w2.x + E2.y*w2.y + E2.z*w2.z + E2.w*w2.w \
                 + E3.x*w3.x + E3.y*w3.y + E3.z*w3.z + E3.w*w3.w;\
        float m = XLV + xrv + ep;                                \
        m = (m > 0.f) ? m : LEAKY * m;   /* leaky_relu */        \
        float p = m * attv;                                      \
        p += __shfl_xor(p, 1, 64);                               \
        p += __shfl_xor(p, 2, 64);                               \
        p += __shfl_xor(p, 4, 64);                               \
        const float ex = __expf(p);                              \
        ns  += ex;                                               \
        acc = fmaf(ex, XLV, acc);                                \
    } while (0)

        if (d > 0) FETCH(0, xlA, a0, a1, a2, a3);
        if (d > 1) FETCH(1, xlB, b0, b1, b2, b3);

        for (int i = 0; i < d; i += 2) {
            COMPUTE(xlA, a0, a1, a2, a3);
            if (i + 2 < d) FETCH(i + 2, xlA, a0, a1, a2, a3);
            if (i + 1 < d) {
                COMPUTE(xlB, b0, b1, b2, b3);
                if (i + 3 < d) FETCH(i + 3, xlB, b0, b1, b2, b3);
            }
        }
#undef FETCH
#undef COMPUTE

        const float a = acc / (ns + SM_EPS);
        const float hv = a + biasv + x[(long long)n * 64 + lane];

        float s = hv;
        #pragma unroll
        for (int off = 32; off; off >>= 1) s += __shfl_xor(s, off, 64);
        const float mu = s * (1.f / 64.f);
        const float dd = hv - mu;
        float v = dd * dd;
        #pragma unroll
        for (int off = 32; off; off >>= 1) v += __shfl_xor(v, off, 64);
        const float var = v * (1.f / 64.f);

        float hn = dd * rsqrtf(var + LN_EPS) * gv + bev;
        out[(long long)n * 64 + lane] = (hn > 0.f) ? hn : 0.f;
    }
}

extern "C" void kernel_launch(void* const* d_in, const int* in_sizes, int n_in,
                              void* d_out, int out_size, void* d_ws, size_t ws_size,
                              hipStream_t stream) {
    (void)n_in; (void)out_size;

    const float* x     = (const float*)d_in[0];
    const int*   ei    = (const int*)d_in[1];
    const float* ea    = (const float*)d_in[2];
    const float* Wl    = (const float*)d_in[3];
    const float* bl    = (const float*)d_in[4];
    const float* Wr    = (const float*)d_in[5];
    const float* br    = (const float*)d_in[6];
    const float* We    = (const float*)d_in[7];
    const float* att   = (const float*)d_in[8];
    const float* bias  = (const float*)d_in[9];
    const float* gamma = (const float*)d_in[10];
    const float* beta  = (const float*)d_in[11];

    const int N = in_sizes[0] / 64;   // x is [N,64]
    const int E = in_sizes[1] / 2;    // edge_index is [2,E]
    const int nbins = (N + (1 << BIN_SHIFT) - 1) >> BIN_SHIFT;

    // ws layout: xl, xr, deg[N], binCnt[MAXBINS], slot2[N*CAP] int2, binArr int2
    float* w = (float*)d_ws;
    float* xl   = w;                      w += (size_t)N * 64;
    float* xr   = w;                      w += (size_t)N * 64;
    int* deg    = (int*)w;
    int* binCnt = deg + N;
    int2* slot2 = (int2*)(binCnt + MAXBINS);
    int2* binArr = slot2 + (size_t)N * CAP;
    const size_t needed = ((char*)(binArr + (size_t)nbins * BCAP)) - (char*)d_ws;

    float* out = (float*)d_out;

    const bool binned = (nbins <= MAXBINS) && (E <= (1 << 21)) &&
                        (ws_size >= needed);

    hipMemsetAsync(deg, 0, ((size_t)N + MAXBINS) * sizeof(int), stream);

    k_node_linear<<<2048, 256, 0, stream>>>(x, Wl, bl, Wr, br, xl, xr, N);

    if (binned) {
        const int nbA = (E + CHUNK_A - 1) / CHUNK_A;
        k_binA<<<nbA, 256, 0, stream>>>(ei, binCnt, binArr, E, nbins);
        k_binB<<<nbins, 256, 0, stream>>>(binCnt, binArr, deg, slot2, N);
    } else {
        k_bucket<<<(E + 255) / 256, 256, 0, stream>>>(ei, deg, slot2, E);
    }

    // 4 waves/block x 4 nodes/wave = 16 nodes/block
    k_gather<<<(N + 16 * 1 - 1) / 16, 256, 0, stream>>>(
        ea, We, att, xl, xr, deg, slot2, x, bias, gamma, beta, out, N);
}